// Round 6
// baseline (110.239 us; speedup 1.0000x reference)
//
#include <hip/hip_runtime.h>

// TemporalPyramidPooling R6: R3 geometry (TILE=32, 2048 single-wave blocks,
// 8 waves/CU) + R5 streaming inner loop (groups of 8 rows, O(1) carries,
// rotating prefetch-2-ahead register buffers, loads/stores interleaved).
// (w,stride) = (4,2), (8,4), (16,8) over x[8,4096,512] fp32.
// Convergence test: if this lands within noise of R3 (109.4us), the kernel
// is at its memory floor and dur_us is dominated by harness reset traffic.

#define EPS 1e-6f

typedef float f4 __attribute__((ext_vector_type(4)));

constexpr int B = 8, T = 4096, D = 512, D4 = D / 4;
constexpr int TILE = 32;          // timesteps per tile
constexpr int NTILES = T / TILE;  // 128
constexpr int S4 = 2047, S8 = 1023, S16 = 511;

constexpr size_t OFF0 = 0;                           // avg4  [B,S4,D]
constexpr size_t OFF1 = (size_t)B * S4 * D;          // avg8  [B,S8,D]
constexpr size_t OFF2 = OFF1 + (size_t)B * S8 * D;   // avg16 [B,S16,D]
constexpr size_t OFF3 = OFF2 + (size_t)B * S16 * D;  // mask4 [B,S4]
constexpr size_t OFF4 = OFF3 + (size_t)B * S4;       // mask8 [B,S8]
constexpr size_t OFF5 = OFF4 + (size_t)B * S8;       // mask16[B,S16]

__device__ __forceinline__ float rcp_clip(float c) {
  return __builtin_amdgcn_rcpf(fmaxf(c, EPS));  // ~1ulp err << 0.08 thresh
}

// NU = 5 for tiles 0..126 (rows t0..t0+39); NU = 4 for tile 127 (rows
// t0..t0+31; windows j=15,k=7,l=3 are globally out of range, never emitted).
// Per group u: 4 masked pairs. In-group outputs (u<4): w4 j=4u..4u+2,
// w8 k=2u. Carry outputs (u>=1): w4 j=4u-1, w8 k=2u-1, w16 l=u-1.
template <int NU>
__device__ __forceinline__ void run_tile(const f4* __restrict__ xb,
                                         const int* __restrict__ mp,
                                         float* __restrict__ out, int b,
                                         int tile, int d4, int lane,
                                         bool wmask) {
  f4 buf[3][8];
  float mfb[3][8];

  // preload groups 0 and 1
#pragma unroll
  for (int g = 0; g < 2; ++g) {
#pragma unroll
    for (int rr = 0; rr < 8; ++rr) {
      buf[g][rr] = xb[(size_t)(8 * g + rr) * D4];
      mfb[g][rr] = (mp[8 * g + rr] != 0) ? 1.f : 0.f;
    }
  }

  f4 P3 = {0.f, 0.f, 0.f, 0.f}, H = {0.f, 0.f, 0.f, 0.f},
     G = {0.f, 0.f, 0.f, 0.f};
  float cP3 = 0.f, cH = 0.f, cG = 0.f;

  f4* o4 = (f4*)(out + OFF0) + ((size_t)b * S4 + (size_t)tile * 16) * D4 + d4;
  f4* o8 = (f4*)(out + OFF1) + ((size_t)b * S8 + (size_t)tile * 8) * D4 + d4;
  f4* o16 = (f4*)(out + OFF2) + ((size_t)b * S16 + (size_t)tile * 4) * D4 + d4;
  float* m4 = out + OFF3 + (size_t)b * S4 + (size_t)tile * 16;
  float* m8 = out + OFF4 + (size_t)b * S8 + (size_t)tile * 8;
  float* m16 = out + OFF5 + (size_t)b * S16 + (size_t)tile * 4;

#pragma unroll
  for (int u = 0; u < NU; ++u) {
    // prefetch group u+2 into the rotating buffer
    if (u + 2 < NU) {
#pragma unroll
      for (int rr = 0; rr < 8; ++rr) {
        buf[(u + 2) % 3][rr] = xb[(size_t)(8 * (u + 2) + rr) * D4];
        mfb[(u + 2) % 3][rr] = (mp[8 * (u + 2) + rr] != 0) ? 1.f : 0.f;
      }
    }

    const f4* r = buf[u % 3];
    const float* mf = mfb[u % 3];

    // 4 masked pairs of this group
    f4 pr0 = r[0] * mf[0] + r[1] * mf[1];
    f4 pr1 = r[2] * mf[2] + r[3] * mf[3];
    f4 pr2 = r[4] * mf[4] + r[5] * mf[5];
    f4 pr3 = r[6] * mf[6] + r[7] * mf[7];
    float c0 = mf[0] + mf[1], c1 = mf[2] + mf[3];
    float c2 = mf[4] + mf[5], c3 = mf[6] + mf[7];
    f4 Gc = (pr0 + pr1) + (pr2 + pr3);
    float cGc = (c0 + c1) + (c2 + c3);

    // carry-based outputs (windows straddling the group boundary)
    if (u >= 1) {
      f4 v;
      v = (P3 + pr0) * rcp_clip(cP3 + c0);  // w4 j = 4u-1
      __builtin_nontemporal_store(v, o4 + (size_t)(4 * u - 1) * D4);
      v = (H + (pr0 + pr1)) * rcp_clip(cH + c0 + c1);  // w8 k = 2u-1
      __builtin_nontemporal_store(v, o8 + (size_t)(2 * u - 1) * D4);
      v = (G + Gc) * rcp_clip(cG + cGc);  // w16 l = u-1
      __builtin_nontemporal_store(v, o16 + (size_t)(u - 1) * D4);
    }
    // in-group outputs
    if (u < 4) {
      f4 v;
      v = (pr0 + pr1) * rcp_clip(c0 + c1);  // w4 j = 4u
      __builtin_nontemporal_store(v, o4 + (size_t)(4 * u + 0) * D4);
      v = (pr1 + pr2) * rcp_clip(c1 + c2);  // w4 j = 4u+1
      __builtin_nontemporal_store(v, o4 + (size_t)(4 * u + 1) * D4);
      v = (pr2 + pr3) * rcp_clip(c2 + c3);  // w4 j = 4u+2
      __builtin_nontemporal_store(v, o4 + (size_t)(4 * u + 2) * D4);
      v = Gc * rcp_clip(cGc);  // w8 k = 2u
      __builtin_nontemporal_store(v, o8 + (size_t)(2 * u) * D4);
    }

    // mask outputs: wave-uniform scalars, one lane each (wmask wave only)
    if (wmask) {
      float cc = 0.f;
      float* ap = nullptr;
      if (u < 4) {
        if (lane == 0) { cc = c0 + c1; ap = m4 + 4 * u; }
        else if (lane == 1) { cc = c1 + c2; ap = m4 + 4 * u + 1; }
        else if (lane == 2) { cc = c2 + c3; ap = m4 + 4 * u + 2; }
        else if (lane == 4) { cc = cGc; ap = m8 + 2 * u; }
      }
      if (u >= 1) {
        if (lane == 3) { cc = cP3 + c0; ap = m4 + 4 * u - 1; }
        else if (lane == 5) { cc = cH + c0 + c1; ap = m8 + 2 * u - 1; }
        else if (lane == 6) { cc = cG + cGc; ap = m16 + u - 1; }
      }
      if (ap) *ap = (cc > 0.f) ? 1.f : 0.f;
    }

    // update carries
    P3 = pr3; H = pr2 + pr3; G = Gc;
    cP3 = c3; cH = c2 + c3; cG = cGc;
  }
}

__global__ __launch_bounds__(64)
void tpp_kernel(const f4* __restrict__ x4, const int* __restrict__ mask,
                float* __restrict__ out) {
  const int lane = threadIdx.x;            // 0..63
  const int d4 = blockIdx.x * 64 + lane;   // 0..127
  const int b = blockIdx.z;
  const int tile = blockIdx.y;
  const bool wmask = (blockIdx.x == 0);

  const f4* xb = x4 + ((size_t)b * T + (size_t)tile * TILE) * D4 + d4;
  const int* mp = mask + (size_t)b * T + tile * TILE;

  if (tile < NTILES - 1)
    run_tile<5>(xb, mp, out, b, tile, d4, lane, wmask);
  else
    run_tile<4>(xb, mp, out, b, tile, d4, lane, wmask);
}

extern "C" void kernel_launch(void* const* d_in, const int* in_sizes, int n_in,
                              void* d_out, int out_size, void* d_ws,
                              size_t ws_size, hipStream_t stream) {
  const f4* x4 = (const f4*)d_in[0];
  const int* mask = (const int*)d_in[1];
  float* out = (float*)d_out;
  dim3 grid(D4 / 64, NTILES, B);  // (2,128,8) = 2048 single-wave blocks
  tpp_kernel<<<grid, 64, 0, stream>>>(x4, mask, out);
}